// Round 1
// baseline (443.181 us; speedup 1.0000x reference)
//
#include <hip/hip_runtime.h>

#define NEGINF (-1e30f)

// ---------------- problem constants ----------------
// b=4, c=64, h=w=5, q=75, u=100, N_WAY=5, K_SHOT=5
// M_s = 125 (per way), M_u = 2500, M_q = 25, M_tot = 2625
// ---------------- workspace layout (float units) ----------------
constexpr size_t OF_UNL  = 0;                              // [4][2500][64]  normalized unl, location-major
constexpr size_t OF_SUP  = OF_UNL  + (size_t)4*2500*64;    // [4][5][125][64] normalized support, column-major-per-loc
constexpr size_t OF_SUPT = OF_SUP  + (size_t)4*5*125*64;   // [4][5][64][128] transposed support (pad 125->128)
constexpr size_t OF_QT   = OF_SUPT + (size_t)4*5*64*128;   // [300][64][25]  transposed normalized query
constexpr size_t OF_ROWV = OF_QT   + (size_t)300*64*25;    // [4][5][2500] f  per-way row-argmax value
constexpr size_t OF_ROWI = OF_ROWV + (size_t)4*5*2500;     // [4][5][2500] i  per-way row-argmax n
constexpr size_t OF_CVI  = OF_ROWI + (size_t)4*5*2500;     // [4][5][125][20][2] col-argmax partials (v, m)
constexpr size_t OF_CMP  = OF_CVI  + (size_t)4*5*125*20*2; // [4][5][2500] i  compacted unl indices
constexpr size_t OF_CNT  = OF_CMP  + (size_t)4*5*2500;     // [20] i counts
constexpr size_t OF_L    = OF_CNT  + 20;                   // [1] i  L = max count  (+3 pad)
constexpr size_t OF_QV   = OF_L    + 4;                    // [300][5] f query_value

// ============================================================
// Kernel A: L2-normalize all three tensors into ws layouts.
// 16 lanes per location, 4 channels per lane.
// loc 0..9999: unl  (b,m)        -> unl_n[b][m][c]
// loc 10000..12499: support      -> sup_n[b][w][n][c] and supT[b][w][c][128]
// loc 12500..19999: query        -> qt[bq][c][25]
// ============================================================
__global__ __launch_bounds__(256) void knorm(
    const float* __restrict__ sup, const float* __restrict__ qry,
    const float* __restrict__ unl,
    float* __restrict__ unl_n, float* __restrict__ sup_n,
    float* __restrict__ supT, float* __restrict__ qt)
{
    int gid = blockIdx.x * 256 + threadIdx.x;
    int loc = gid >> 4;
    int sub = gid & 15;
    if (loc >= 20000) return;

    const float* src;
    float* dst1; int dstr1;
    float* dst2 = nullptr;

    if (loc < 10000) {
        int b = loc / 2500, m = loc % 2500;
        int u = m / 25, hw = m % 25;
        src  = unl + ((size_t)(b*100 + u) * 64) * 25 + hw;   // + c*25
        dst1 = unl_n + (size_t)loc * 64; dstr1 = 1;
    } else if (loc < 12500) {
        int idx = loc - 10000;
        int b = idx / 625, r = idx % 625;
        int w = r / 125,  n = r % 125;
        int shot = n / 25, hw = n % 25;
        src  = sup + ((size_t)(b*25 + w*5 + shot) * 64) * 25 + hw;
        dst1 = sup_n + (size_t)idx * 64; dstr1 = 1;
        dst2 = supT + ((size_t)(b*5 + w) * 64) * 128 + n;    // + c*128
    } else {
        int idx = loc - 12500;
        int bq = idx / 25, mq = idx % 25;
        src  = qry + ((size_t)bq * 64) * 25 + mq;
        dst1 = qt + ((size_t)bq * 64) * 25 + mq; dstr1 = 25;
    }

    float v[4]; float ss = 0.f;
    int c0 = sub * 4;
#pragma unroll
    for (int j = 0; j < 4; ++j) { v[j] = src[(size_t)(c0 + j) * 25]; ss += v[j] * v[j]; }
#pragma unroll
    for (int msk = 1; msk < 16; msk <<= 1) ss += __shfl_xor(ss, msk);
    float sc = 1.f / fmaxf(sqrtf(ss), 1e-12f);
#pragma unroll
    for (int j = 0; j < 4; ++j) {
        float o = v[j] * sc;
        dst1[(size_t)(c0 + j) * dstr1] = o;
        if (dst2) dst2[(size_t)(c0 + j) * 128] = o;
    }
}

// ============================================================
// Kernel B: u2s pass. grid = b*5ways*20mblocks = 400 blocks, 128 threads.
// lane-per-m (128 m's staged in LDS, stride 65 = conflict-free),
// support operand via wave-uniform reads of supT (scalar pipe).
// Outputs: rowv/rowi[b][w][m]  (per-way row argmax, first-tie)
//          colvi[b][w][n][mb]  (per-mblock col argmax (v, m), min-m tie)
// ============================================================
__global__ __launch_bounds__(128) void kb(
    const float* __restrict__ unl_n, const float* __restrict__ supT,
    float* __restrict__ rowv, int* __restrict__ rowi, float* __restrict__ colvi)
{
    int bid = blockIdx.x;
    int mb = bid % 20; int w = (bid / 20) % 5; int b = bid / 100;
    int tid = threadIdx.x;
    int lane = tid & 63, wv = tid >> 6;

    __shared__ float uls[128 * 65];
    __shared__ float sv_[2][16];
    __shared__ int   si_[2][16];

    int m0 = mb * 128;
    // stage 128 unl rows (zero-fill past 2500)
    for (int i = tid; i < 128 * 16; i += 128) {
        int row = i >> 4, c4 = (i & 15) * 4;
        int m = m0 + row;
        float4 x = make_float4(0.f, 0.f, 0.f, 0.f);
        if (m < 2500) x = *(const float4*)(unl_n + ((size_t)(b * 2500 + m)) * 64 + c4);
        uls[row * 65 + c4 + 0] = x.x;
        uls[row * 65 + c4 + 1] = x.y;
        uls[row * 65 + c4 + 2] = x.z;
        uls[row * 65 + c4 + 3] = x.w;
    }
    __syncthreads();

    int m = m0 + tid;
    const float* sT = supT + ((size_t)(b * 5 + w) * 64) * 128;
    const float* myrow = &uls[tid * 65];
    float rbv = NEGINF; int rbi = 0;

    for (int n0 = 0; n0 < 125; n0 += 16) {
        int nn = (125 - n0) < 16 ? (125 - n0) : 16;
        float acc[16];
#pragma unroll
        for (int j = 0; j < 16; ++j) acc[j] = 0.f;
        for (int c = 0; c < 64; ++c) {
            float uv = myrow[c];
            const float* srow = sT + c * 128 + n0;
#pragma unroll
            for (int j = 0; j < 16; ++j) acc[j] = fmaf(uv, srow[j], acc[j]);
        }
        // row-side running argmax (ascending n, strict > keeps first)
        for (int j = 0; j < nn; ++j)
            if (acc[j] > rbv) { rbv = acc[j]; rbi = n0 + j; }
        // col-side cross-lane argmax (min-m tie)
#pragma unroll
        for (int j = 0; j < 16; ++j) {
            float v = (m < 2500 && j < nn) ? acc[j] : NEGINF;
            int vi = m;
#pragma unroll
            for (int s2 = 1; s2 < 64; s2 <<= 1) {
                float v2 = __shfl_xor(v, s2); int i2 = __shfl_xor(vi, s2);
                if (v2 > v || (v2 == v && i2 < vi)) { v = v2; vi = i2; }
            }
            if (lane == 0) { sv_[wv][j] = v; si_[wv][j] = vi; }
        }
        __syncthreads();
        if (tid < nn) {
            float v = sv_[0][tid]; int vi = si_[0][tid];
            float v2 = sv_[1][tid]; int i2 = si_[1][tid];
            if (v2 > v || (v2 == v && i2 < vi)) { v = v2; vi = i2; }
            float* cv = colvi + ((((size_t)(b * 5 + w)) * 125 + (n0 + tid)) * 20 + mb) * 2;
            cv[0] = v; ((int*)cv)[1] = vi;
        }
        __syncthreads();
    }
    if (m < 2500) {
        rowv[((size_t)(b * 5 + w)) * 2500 + m] = rbv;
        rowi[((size_t)(b * 5 + w)) * 2500 + m] = rbi;
    }
}

// ============================================================
// Kernel B3: merge partials; mutual-NN mask; stable stream compaction.
// Single block, 256 threads.
// ============================================================
__global__ __launch_bounds__(256) void kb3(
    const float* __restrict__ rowv, const int* __restrict__ rowi,
    const float* __restrict__ colvi,
    int* __restrict__ cmp, int* __restrict__ cntg, int* __restrict__ Lp)
{
    __shared__ int unear[4 * 2500];
    __shared__ int snear[4 * 625];
    __shared__ int cl[20];
    int tid = threadIdx.x;

    // merge row partials over 5 ways (ascending w, strict > = first-tie)
    for (int it = tid; it < 10000; it += 256) {
        int b = it / 2500, m = it % 2500;
        float bv = NEGINF; int bi = 0;
#pragma unroll
        for (int w = 0; w < 5; ++w) {
            float v = rowv[((size_t)(b * 5 + w)) * 2500 + m];
            if (v > bv) { bv = v; bi = w * 125 + rowi[((size_t)(b * 5 + w)) * 2500 + m]; }
        }
        unear[it] = bi;
    }
    // merge col partials over 20 mblocks (min-m tie)
    for (int it = tid; it < 2500; it += 256) {
        const float* p = colvi + (size_t)it * 40;
        float bv = NEGINF; int bi = 0;
        for (int mb2 = 0; mb2 < 20; ++mb2) {
            float v = p[mb2 * 2]; int vi = ((const int*)p)[mb2 * 2 + 1];
            if (v > bv || (v == bv && vi < bi)) { bv = v; bi = vi; }
        }
        snear[it] = bi;
    }
    __syncthreads();

    // mutual & stable compaction: wave per (b,way)
    int wv = tid >> 6, lane = tid & 63;
    for (int p = wv; p < 20; p += 4) {
        int b = p / 5, way = p % 5;
        int base = 0;
        for (int mc = 0; mc < 2500; mc += 64) {
            int m = mc + lane;
            bool ok = false;
            if (m < 2500) {
                int un = unear[b * 2500 + m];
                ok = (un / 125 == way) && (snear[b * 625 + un] == m);
            }
            unsigned long long msk = __ballot(ok ? 1 : 0);
            int pre = __popcll(msk & ((1ull << lane) - 1ull));
            if (ok) cmp[((size_t)(b * 5 + way)) * 2500 + base + pre] = m;
            base += __popcll(msk);
        }
        if (lane == 0) { cl[p] = base; cntg[p] = base; }
    }
    __syncthreads();
    if (tid == 0) {
        int L = 0;
        for (int p = 0; p < 20; ++p) L = L > cl[p] ? L : cl[p];
        Lp[0] = L;
    }
}

// ============================================================
// Kernel C: the hot kernel. One block (256 thr) per (b,q).
// lane-per-column over real columns only (support + compacted unl);
// phantom (all-zero) columns handled analytically (sim == 0.5).
// Tracks: per-(w,mq) max; per-mq best (val, jf<<12|pos) with exact
// first-index tie-break; per-column argmax-over-mq into LDS.
// Epilogue: mutual mask -> query_value[bq][5].
// ============================================================
__global__ __launch_bounds__(256) void kc(
    const float* __restrict__ qt, const float* __restrict__ sup_n,
    const float* __restrict__ unl_n, const int* __restrict__ cmp,
    const int* __restrict__ cntg, const int* __restrict__ Lp,
    float* __restrict__ qv)
{
    int bq = blockIdx.x;
    int b = bq / 75;
    int tid = threadIdx.x;
    int lane = tid & 63, wv = tid >> 6;

    const float* qtb = qt + (size_t)bq * 64 * 25;
    int cnt[5];
#pragma unroll
    for (int w = 0; w < 5; ++w) cnt[w] = cntg[b * 5 + w];
    int L = Lp[0];
    int wb[5];
    { int s = 0;
#pragma unroll
      for (int w = 0; w < 5; ++w) { wb[w] = s; s += 125 + cnt[w]; } }

    __shared__ unsigned char amax_[3136];
    __shared__ float wmaxl[5][25];
    __shared__ float redf[4][25];
    __shared__ int   redi[4][25];
    __shared__ float qmask[25];

    float bestv[25]; int bestp[25];
#pragma unroll
    for (int i = 0; i < 25; ++i) { bestv[i] = NEGINF; bestp[i] = 0x7fffffff; }

    for (int w = 0; w < 5; ++w) {
        float wmx[25];
#pragma unroll
        for (int i = 0; i < 25; ++i) wmx[i] = NEGINF;
        int cw = 125 + cnt[w];

        for (int n = tid; n < cw; n += 256) {
            const float* colp;
            if (n < 125) colp = sup_n + (((size_t)(b * 5 + w)) * 125 + n) * 64;
            else {
                int m = cmp[((size_t)(b * 5 + w)) * 2500 + (n - 125)];
                colp = unl_n + ((size_t)(b * 2500 + m)) * 64;
            }
            float acc[25];
#pragma unroll
            for (int i = 0; i < 25; ++i) acc[i] = 0.f;
            for (int c = 0; c < 64; c += 4) {
                float4 cv = *(const float4*)(colp + c);
                const float* qr = qtb + c * 25;   // wave-uniform -> scalar loads
#pragma unroll
                for (int mq = 0; mq < 25; ++mq) {
                    acc[mq] = fmaf(cv.x, qr[mq],      acc[mq]);
                    acc[mq] = fmaf(cv.y, qr[25 + mq], acc[mq]);
                    acc[mq] = fmaf(cv.z, qr[50 + mq], acc[mq]);
                    acc[mq] = fmaf(cv.w, qr[75 + mq], acc[mq]);
                }
            }
            float cmax = NEGINF; int cam = 0;
            int pos = wb[w] + n;
            int pack = ((w * 2625 + n) << 12) | pos;
#pragma unroll
            for (int mq = 0; mq < 25; ++mq) {
                float s = (acc[mq] + 1.0f) * 0.5f;
                if (s > cmax) { cmax = s; cam = mq; }
                wmx[mq] = fmaxf(wmx[mq], s);
                if (s > bestv[mq] || (s == bestv[mq] && pack < bestp[mq])) {
                    bestv[mq] = s; bestp[mq] = pack;
                }
            }
            amax_[pos] = (unsigned char)cam;
        }

        // phantom (zero) columns: value 0.5, first one at n = 125+cnt[w]
        if (L > cnt[w]) {
            int pack = ((w * 2625 + 125 + cnt[w]) << 12) | 0xFFF;
#pragma unroll
            for (int mq = 0; mq < 25; ++mq) {
                float s = 0.5f;
                if (s > bestv[mq] || (s == bestv[mq] && pack < bestp[mq])) {
                    bestv[mq] = s; bestp[mq] = pack;
                }
            }
        }

        // reduce per-(w,mq) max across block
#pragma unroll
        for (int mq = 0; mq < 25; ++mq) {
            float v = wmx[mq];
#pragma unroll
            for (int s2 = 1; s2 < 64; s2 <<= 1) v = fmaxf(v, __shfl_xor(v, s2));
            wmx[mq] = v;
        }
        if (lane == 0) {
#pragma unroll
            for (int mq = 0; mq < 25; ++mq) redf[wv][mq] = wmx[mq];
        }
        __syncthreads();
        if (tid < 25) {
            float v = fmaxf(fmaxf(redf[0][tid], redf[1][tid]),
                            fmaxf(redf[2][tid], redf[3][tid]));
            if (L > cnt[w]) v = fmaxf(v, 0.5f);
            wmaxl[w][tid] = v;
        }
        __syncthreads();
    }

    // reduce per-mq best (val, pack) across block
#pragma unroll
    for (int mq = 0; mq < 25; ++mq) {
        float v = bestv[mq]; int p = bestp[mq];
#pragma unroll
        for (int s2 = 1; s2 < 64; s2 <<= 1) {
            float v2 = __shfl_xor(v, s2); int p2 = __shfl_xor(p, s2);
            if (v2 > v || (v2 == v && p2 < p)) { v = v2; p = p2; }
        }
        bestv[mq] = v; bestp[mq] = p;
    }
    if (lane == 0) {
#pragma unroll
        for (int mq = 0; mq < 25; ++mq) { redf[wv][mq] = bestv[mq]; redi[wv][mq] = bestp[mq]; }
    }
    __syncthreads();
    if (tid < 25) {
        float v = redf[0][tid]; int p = redi[0][tid];
#pragma unroll
        for (int k = 1; k < 4; ++k) {
            float v2 = redf[k][tid]; int p2 = redi[k][tid];
            if (v2 > v || (v2 == v && p2 < p)) { v = v2; p = p2; }
        }
        int pos = p & 0xFFF;
        int g = (pos == 0xFFF) ? 0 : (int)amax_[pos];
        qmask[tid] = (g == tid) ? 1.0f : 0.0f;
    }
    __syncthreads();
    if (tid < 5) {
        float s = 0.f;
#pragma unroll
        for (int mq = 0; mq < 25; ++mq) s += wmaxl[tid][mq] * qmask[mq];
        qv[(size_t)bq * 5 + tid] = s;
    }
}

// ============================================================
// Kernel D: cross-entropy loss over 300 rows of 5 logits.
// ============================================================
__global__ __launch_bounds__(256) void kd(
    const float* __restrict__ qv, const int* __restrict__ qy,
    float* __restrict__ out)
{
    __shared__ float part[256];
    int tid = threadIdx.x;
    float s = 0.f;
    for (int r = tid; r < 300; r += 256) {
        const float* l = qv + (size_t)r * 5;
        int y = qy[r];
        float mx = l[0];
#pragma unroll
        for (int w = 1; w < 5; ++w) mx = fmaxf(mx, l[w]);
        float se = 0.f;
#pragma unroll
        for (int w = 0; w < 5; ++w) se += expf(l[w] - mx);
        s += -(l[y] - mx - logf(se));
    }
    part[tid] = s;
    __syncthreads();
    for (int st = 128; st > 0; st >>= 1) {
        if (tid < st) part[tid] += part[tid + st];
        __syncthreads();
    }
    if (tid == 0) out[0] = part[0] / 300.0f;
}

// ============================================================
extern "C" void kernel_launch(void* const* d_in, const int* in_sizes, int n_in,
                              void* d_out, int out_size, void* d_ws, size_t ws_size,
                              hipStream_t stream)
{
    const float* sup = (const float*)d_in[0];
    // d_in[1] = support_y (unused by the forward pass)
    const float* qry = (const float*)d_in[2];
    const int*   qy  = (const int*)d_in[3];
    const float* unl = (const float*)d_in[4];

    float* ws    = (float*)d_ws;
    float* unl_n = ws + OF_UNL;
    float* sup_n = ws + OF_SUP;
    float* supT  = ws + OF_SUPT;
    float* qt    = ws + OF_QT;
    float* rowv  = ws + OF_ROWV;
    int*   rowi  = (int*)(ws + OF_ROWI);
    float* colvi = ws + OF_CVI;
    int*   cmp   = (int*)(ws + OF_CMP);
    int*   cntg  = (int*)(ws + OF_CNT);
    int*   Lp    = (int*)(ws + OF_L);
    float* qv    = ws + OF_QV;

    hipLaunchKernelGGL(knorm, dim3(1250), dim3(256), 0, stream,
                       sup, qry, unl, unl_n, sup_n, supT, qt);
    hipLaunchKernelGGL(kb, dim3(400), dim3(128), 0, stream,
                       unl_n, supT, rowv, rowi, colvi);
    hipLaunchKernelGGL(kb3, dim3(1), dim3(256), 0, stream,
                       rowv, rowi, colvi, cmp, cntg, Lp);
    hipLaunchKernelGGL(kc, dim3(300), dim3(256), 0, stream,
                       qt, sup_n, unl_n, cmp, cntg, Lp, qv);
    hipLaunchKernelGGL(kd, dim3(1), dim3(256), 0, stream,
                       qv, qy, (float*)d_out);
}

// Round 2
// 305.475 us; speedup vs baseline: 1.4508x; 1.4508x over previous
//
#include <hip/hip_runtime.h>

#define NEGINF (-1e30f)

// ---------------- problem constants ----------------
// b=4, c=64, h=w=5, q=75, u=100, N_WAY=5, K_SHOT=5
// M_s = 125 (per way), M_u = 2500, M_q = 25, M_tot = 2625
// ---------------- workspace layout (float units) ----------------
constexpr size_t OF_UNL  = 0;                              // [4][2500][64]  normalized unl, location-major
constexpr size_t OF_SUP  = OF_UNL  + (size_t)4*2500*64;    // [4][5][125][64] normalized support
constexpr size_t OF_SUPT = OF_SUP  + (size_t)4*5*125*64;   // [4][5][64][128] transposed support (pad 125->128)
constexpr size_t OF_QT   = OF_SUPT + (size_t)4*5*64*128;   // [300][64][25]  transposed normalized query
constexpr size_t OF_ROWV = OF_QT   + (size_t)300*64*25;    // [4][5][2500] f  per-way row-argmax value
constexpr size_t OF_ROWI = OF_ROWV + (size_t)4*5*2500;     // [4][5][2500] i  per-way row-argmax n
constexpr size_t OF_CVI  = OF_ROWI + (size_t)4*5*2500;     // [4][5][125][20][2] col-argmax partials (v, m)
constexpr size_t OF_CMP  = OF_CVI  + (size_t)4*5*125*20*2; // [4][5][2500] i  compacted unl indices
constexpr size_t OF_CNT  = OF_CMP  + (size_t)4*5*2500;     // [20] i counts
constexpr size_t OF_QV   = OF_CNT  + 20;                   // [300][5] f query_value
constexpr size_t OF_UNEAR= OF_QV   + 1500;                 // [4][2500] i  per-unl-loc nearest support loc
constexpr size_t OF_SNEAR= OF_UNEAR+ 10000;                // [4][625]  i  per-support-loc nearest unl loc

// ============================================================
// Kernel A: L2-normalize all three tensors into ws layouts.
// 16 lanes per location, 4 channels per lane.
// ============================================================
__global__ __launch_bounds__(256) void knorm(
    const float* __restrict__ sup, const float* __restrict__ qry,
    const float* __restrict__ unl,
    float* __restrict__ unl_n, float* __restrict__ sup_n,
    float* __restrict__ supT, float* __restrict__ qt)
{
    int gid = blockIdx.x * 256 + threadIdx.x;
    int loc = gid >> 4;
    int sub = gid & 15;
    if (loc >= 20000) return;

    const float* src;
    float* dst1; int dstr1;
    float* dst2 = nullptr;

    if (loc < 10000) {
        int b = loc / 2500, m = loc % 2500;
        int u = m / 25, hw = m % 25;
        src  = unl + ((size_t)(b*100 + u) * 64) * 25 + hw;   // + c*25
        dst1 = unl_n + (size_t)loc * 64; dstr1 = 1;
    } else if (loc < 12500) {
        int idx = loc - 10000;
        int b = idx / 625, r = idx % 625;
        int w = r / 125,  n = r % 125;
        int shot = n / 25, hw = n % 25;
        src  = sup + ((size_t)(b*25 + w*5 + shot) * 64) * 25 + hw;
        dst1 = sup_n + (size_t)idx * 64; dstr1 = 1;
        dst2 = supT + ((size_t)(b*5 + w) * 64) * 128 + n;    // + c*128
    } else {
        int idx = loc - 12500;
        int bq = idx / 25, mq = idx % 25;
        src  = qry + ((size_t)bq * 64) * 25 + mq;
        dst1 = qt + ((size_t)bq * 64) * 25 + mq; dstr1 = 25;
    }

    float v[4]; float ss = 0.f;
    int c0 = sub * 4;
#pragma unroll
    for (int j = 0; j < 4; ++j) { v[j] = src[(size_t)(c0 + j) * 25]; ss += v[j] * v[j]; }
#pragma unroll
    for (int msk = 1; msk < 16; msk <<= 1) ss += __shfl_xor(ss, msk);
    float sc = 1.f / fmaxf(sqrtf(ss), 1e-12f);
#pragma unroll
    for (int j = 0; j < 4; ++j) {
        float o = v[j] * sc;
        dst1[(size_t)(c0 + j) * dstr1] = o;
        if (dst2) dst2[(size_t)(c0 + j) * 128] = o;
    }
}

// ============================================================
// Kernel B: u2s pass. grid = b*5ways*20mblocks = 400 blocks, 128 threads.
// ============================================================
__global__ __launch_bounds__(128) void kb(
    const float* __restrict__ unl_n, const float* __restrict__ supT,
    float* __restrict__ rowv, int* __restrict__ rowi, float* __restrict__ colvi)
{
    int bid = blockIdx.x;
    int mb = bid % 20; int w = (bid / 20) % 5; int b = bid / 100;
    int tid = threadIdx.x;
    int lane = tid & 63, wv = tid >> 6;

    __shared__ float uls[128 * 65];
    __shared__ float sv_[2][16];
    __shared__ int   si_[2][16];

    int m0 = mb * 128;
    for (int i = tid; i < 128 * 16; i += 128) {
        int row = i >> 4, c4 = (i & 15) * 4;
        int m = m0 + row;
        float4 x = make_float4(0.f, 0.f, 0.f, 0.f);
        if (m < 2500) x = *(const float4*)(unl_n + ((size_t)(b * 2500 + m)) * 64 + c4);
        uls[row * 65 + c4 + 0] = x.x;
        uls[row * 65 + c4 + 1] = x.y;
        uls[row * 65 + c4 + 2] = x.z;
        uls[row * 65 + c4 + 3] = x.w;
    }
    __syncthreads();

    int m = m0 + tid;
    const float* sT = supT + ((size_t)(b * 5 + w) * 64) * 128;
    const float* myrow = &uls[tid * 65];
    float rbv = NEGINF; int rbi = 0;

    for (int n0 = 0; n0 < 125; n0 += 16) {
        int nn = (125 - n0) < 16 ? (125 - n0) : 16;
        float acc[16];
#pragma unroll
        for (int j = 0; j < 16; ++j) acc[j] = 0.f;
        for (int c = 0; c < 64; ++c) {
            float uv = myrow[c];
            const float* srow = sT + c * 128 + n0;
#pragma unroll
            for (int j = 0; j < 16; ++j) acc[j] = fmaf(uv, srow[j], acc[j]);
        }
        for (int j = 0; j < nn; ++j)
            if (acc[j] > rbv) { rbv = acc[j]; rbi = n0 + j; }
#pragma unroll
        for (int j = 0; j < 16; ++j) {
            float v = (m < 2500 && j < nn) ? acc[j] : NEGINF;
            int vi = m;
#pragma unroll
            for (int s2 = 1; s2 < 64; s2 <<= 1) {
                float v2 = __shfl_xor(v, s2); int i2 = __shfl_xor(vi, s2);
                if (v2 > v || (v2 == v && i2 < vi)) { v = v2; vi = i2; }
            }
            if (lane == 0) { sv_[wv][j] = v; si_[wv][j] = vi; }
        }
        __syncthreads();
        if (tid < nn) {
            float v = sv_[0][tid]; int vi = si_[0][tid];
            float v2 = sv_[1][tid]; int i2 = si_[1][tid];
            if (v2 > v || (v2 == v && i2 < vi)) { v = v2; vi = i2; }
            float* cv = colvi + ((((size_t)(b * 5 + w)) * 125 + (n0 + tid)) * 20 + mb) * 2;
            cv[0] = v; ((int*)cv)[1] = vi;
        }
        __syncthreads();
    }
    if (m < 2500) {
        rowv[((size_t)(b * 5 + w)) * 2500 + m] = rbv;
        rowi[((size_t)(b * 5 + w)) * 2500 + m] = rbi;
    }
}

// ============================================================
// Kernel M: grid-parallel merge of row partials (items 0..9999 -> unear)
// and col partials (items 10000..12499 -> snear). 49 blocks x 256.
// ============================================================
__global__ __launch_bounds__(256) void kmerge(
    const float* __restrict__ rowv, const int* __restrict__ rowi,
    const float* __restrict__ colvi,
    int* __restrict__ unear, int* __restrict__ snear)
{
    int it = blockIdx.x * 256 + threadIdx.x;
    if (it < 10000) {
        int b = it / 2500, m = it % 2500;
        float bv = NEGINF; int bi = 0;
#pragma unroll
        for (int w = 0; w < 5; ++w) {
            float v = rowv[((size_t)(b * 5 + w)) * 2500 + m];
            if (v > bv) { bv = v; bi = w * 125 + rowi[((size_t)(b * 5 + w)) * 2500 + m]; }
        }
        unear[it] = bi;
    } else if (it < 12500) {
        int idx = it - 10000;
        const float* p = colvi + (size_t)idx * 40;
        float bv = NEGINF; int bi = 0x7fffffff;
        for (int mb2 = 0; mb2 < 20; ++mb2) {
            float v = p[mb2 * 2]; int vi = ((const int*)p)[mb2 * 2 + 1];
            if (v > bv || (v == bv && vi < bi)) { bv = v; bi = vi; }
        }
        snear[idx] = bi;
    }
}

// ============================================================
// Kernel P: mutual-NN mask + stable stream compaction.
// One wave per (b,way): 20 blocks x 64 threads.
// ============================================================
__global__ __launch_bounds__(64) void kcmp(
    const int* __restrict__ unear, const int* __restrict__ snear,
    int* __restrict__ cmp, int* __restrict__ cntg)
{
    int p = blockIdx.x;
    int b = p / 5, way = p % 5;
    int lane = threadIdx.x;
    int base = 0;
    for (int mc = 0; mc < 2500; mc += 64) {
        int m = mc + lane;
        bool ok = false;
        if (m < 2500) {
            int un = unear[b * 2500 + m];
            ok = (un / 125 == way) && (snear[b * 625 + un] == m);
        }
        unsigned long long msk = __ballot(ok ? 1 : 0);
        int pre = __popcll(msk & ((1ull << lane) - 1ull));
        if (ok) cmp[(size_t)p * 2500 + base + pre] = m;
        base += __popcll(msk);
    }
    if (lane == 0) cntg[p] = base;
}

// ============================================================
// Kernel C: the hot kernel. One block (256 thr) per (b,q).
// ============================================================
__global__ __launch_bounds__(256) void kc(
    const float* __restrict__ qt, const float* __restrict__ sup_n,
    const float* __restrict__ unl_n, const int* __restrict__ cmp,
    const int* __restrict__ cntg,
    float* __restrict__ qv)
{
    int bq = blockIdx.x;
    int b = bq / 75;
    int tid = threadIdx.x;
    int lane = tid & 63, wv = tid >> 6;

    const float* qtb = qt + (size_t)bq * 64 * 25;
    int cnt[5];
    int L = 0;
#pragma unroll
    for (int i = 0; i < 20; ++i) { int v = cntg[i]; L = L > v ? L : v; }
#pragma unroll
    for (int w = 0; w < 5; ++w) cnt[w] = cntg[b * 5 + w];
    int wb[5];
    { int s = 0;
#pragma unroll
      for (int w = 0; w < 5; ++w) { wb[w] = s; s += 125 + cnt[w]; } }

    __shared__ unsigned char amax_[3136];
    __shared__ float wmaxl[5][25];
    __shared__ float redf[4][25];
    __shared__ int   redi[4][25];
    __shared__ float qmask[25];

    float bestv[25]; int bestp[25];
#pragma unroll
    for (int i = 0; i < 25; ++i) { bestv[i] = NEGINF; bestp[i] = 0x7fffffff; }

    for (int w = 0; w < 5; ++w) {
        float wmx[25];
#pragma unroll
        for (int i = 0; i < 25; ++i) wmx[i] = NEGINF;
        int cw = 125 + cnt[w];

        for (int n = tid; n < cw; n += 256) {
            const float* colp;
            if (n < 125) colp = sup_n + (((size_t)(b * 5 + w)) * 125 + n) * 64;
            else {
                int m = cmp[((size_t)(b * 5 + w)) * 2500 + (n - 125)];
                colp = unl_n + ((size_t)(b * 2500 + m)) * 64;
            }
            float acc[25];
#pragma unroll
            for (int i = 0; i < 25; ++i) acc[i] = 0.f;
            for (int c = 0; c < 64; c += 4) {
                float4 cv = *(const float4*)(colp + c);
                const float* qr = qtb + c * 25;   // block-uniform -> scalar loads
#pragma unroll
                for (int mq = 0; mq < 25; ++mq) {
                    acc[mq] = fmaf(cv.x, qr[mq],      acc[mq]);
                    acc[mq] = fmaf(cv.y, qr[25 + mq], acc[mq]);
                    acc[mq] = fmaf(cv.z, qr[50 + mq], acc[mq]);
                    acc[mq] = fmaf(cv.w, qr[75 + mq], acc[mq]);
                }
            }
            float cmax = NEGINF; int cam = 0;
            int pos = wb[w] + n;
            int pack = ((w * 2625 + n) << 12) | pos;
#pragma unroll
            for (int mq = 0; mq < 25; ++mq) {
                float s = (acc[mq] + 1.0f) * 0.5f;
                if (s > cmax) { cmax = s; cam = mq; }
                wmx[mq] = fmaxf(wmx[mq], s);
                if (s > bestv[mq] || (s == bestv[mq] && pack < bestp[mq])) {
                    bestv[mq] = s; bestp[mq] = pack;
                }
            }
            amax_[pos] = (unsigned char)cam;
        }

        // phantom (all-zero) columns: sim == 0.5, first at n = 125+cnt[w]
        if (L > cnt[w]) {
            int pack = ((w * 2625 + 125 + cnt[w]) << 12) | 0xFFF;
#pragma unroll
            for (int mq = 0; mq < 25; ++mq) {
                float s = 0.5f;
                if (s > bestv[mq] || (s == bestv[mq] && pack < bestp[mq])) {
                    bestv[mq] = s; bestp[mq] = pack;
                }
            }
        }

#pragma unroll
        for (int mq = 0; mq < 25; ++mq) {
            float v = wmx[mq];
#pragma unroll
            for (int s2 = 1; s2 < 64; s2 <<= 1) v = fmaxf(v, __shfl_xor(v, s2));
            wmx[mq] = v;
        }
        if (lane == 0) {
#pragma unroll
            for (int mq = 0; mq < 25; ++mq) redf[wv][mq] = wmx[mq];
        }
        __syncthreads();
        if (tid < 25) {
            float v = fmaxf(fmaxf(redf[0][tid], redf[1][tid]),
                            fmaxf(redf[2][tid], redf[3][tid]));
            if (L > cnt[w]) v = fmaxf(v, 0.5f);
            wmaxl[w][tid] = v;
        }
        __syncthreads();
    }

#pragma unroll
    for (int mq = 0; mq < 25; ++mq) {
        float v = bestv[mq]; int p = bestp[mq];
#pragma unroll
        for (int s2 = 1; s2 < 64; s2 <<= 1) {
            float v2 = __shfl_xor(v, s2); int p2 = __shfl_xor(p, s2);
            if (v2 > v || (v2 == v && p2 < p)) { v = v2; p = p2; }
        }
        bestv[mq] = v; bestp[mq] = p;
    }
    if (lane == 0) {
#pragma unroll
        for (int mq = 0; mq < 25; ++mq) { redf[wv][mq] = bestv[mq]; redi[wv][mq] = bestp[mq]; }
    }
    __syncthreads();
    if (tid < 25) {
        float v = redf[0][tid]; int p = redi[0][tid];
#pragma unroll
        for (int k = 1; k < 4; ++k) {
            float v2 = redf[k][tid]; int p2 = redi[k][tid];
            if (v2 > v || (v2 == v && p2 < p)) { v = v2; p = p2; }
        }
        int pos = p & 0xFFF;
        int g = (pos == 0xFFF) ? 0 : (int)amax_[pos];
        qmask[tid] = (g == tid) ? 1.0f : 0.0f;
    }
    __syncthreads();
    if (tid < 5) {
        float s = 0.f;
#pragma unroll
        for (int mq = 0; mq < 25; ++mq) s += wmaxl[tid][mq] * qmask[mq];
        qv[(size_t)bq * 5 + tid] = s;
    }
}

// ============================================================
// Kernel D: cross-entropy loss over 300 rows of 5 logits.
// ============================================================
__global__ __launch_bounds__(256) void kd(
    const float* __restrict__ qv, const int* __restrict__ qy,
    float* __restrict__ out)
{
    __shared__ float part[256];
    int tid = threadIdx.x;
    float s = 0.f;
    for (int r = tid; r < 300; r += 256) {
        const float* l = qv + (size_t)r * 5;
        int y = qy[r];
        float mx = l[0];
#pragma unroll
        for (int w = 1; w < 5; ++w) mx = fmaxf(mx, l[w]);
        float se = 0.f;
#pragma unroll
        for (int w = 0; w < 5; ++w) se += expf(l[w] - mx);
        s += -(l[y] - mx - logf(se));
    }
    part[tid] = s;
    __syncthreads();
    for (int st = 128; st > 0; st >>= 1) {
        if (tid < st) part[tid] += part[tid + st];
        __syncthreads();
    }
    if (tid == 0) out[0] = part[0] / 300.0f;
}

// ============================================================
extern "C" void kernel_launch(void* const* d_in, const int* in_sizes, int n_in,
                              void* d_out, int out_size, void* d_ws, size_t ws_size,
                              hipStream_t stream)
{
    const float* sup = (const float*)d_in[0];
    const float* qry = (const float*)d_in[2];
    const int*   qy  = (const int*)d_in[3];
    const float* unl = (const float*)d_in[4];

    float* ws    = (float*)d_ws;
    float* unl_n = ws + OF_UNL;
    float* sup_n = ws + OF_SUP;
    float* supT  = ws + OF_SUPT;
    float* qt    = ws + OF_QT;
    float* rowv  = ws + OF_ROWV;
    int*   rowi  = (int*)(ws + OF_ROWI);
    float* colvi = ws + OF_CVI;
    int*   cmp   = (int*)(ws + OF_CMP);
    int*   cntg  = (int*)(ws + OF_CNT);
    float* qv    = ws + OF_QV;
    int*   unear = (int*)(ws + OF_UNEAR);
    int*   snear = (int*)(ws + OF_SNEAR);

    hipLaunchKernelGGL(knorm, dim3(1250), dim3(256), 0, stream,
                       sup, qry, unl, unl_n, sup_n, supT, qt);
    hipLaunchKernelGGL(kb, dim3(400), dim3(128), 0, stream,
                       unl_n, supT, rowv, rowi, colvi);
    hipLaunchKernelGGL(kmerge, dim3(49), dim3(256), 0, stream,
                       rowv, rowi, colvi, unear, snear);
    hipLaunchKernelGGL(kcmp, dim3(20), dim3(64), 0, stream,
                       unear, snear, cmp, cntg);
    hipLaunchKernelGGL(kc, dim3(300), dim3(256), 0, stream,
                       qt, sup_n, unl_n, cmp, cntg, qv);
    hipLaunchKernelGGL(kd, dim3(1), dim3(256), 0, stream,
                       qv, qy, (float*)d_out);
}

// Round 3
// 251.784 us; speedup vs baseline: 1.7602x; 1.2132x over previous
//
#include <hip/hip_runtime.h>

#define NEGINF (-1e30f)

// ---------------- problem constants ----------------
// b=4, c=64, h=w=5, q=75, u=100, N_WAY=5, K_SHOT=5
// M_s = 125 (per way), M_u = 2500, M_q = 25, M_tot = 2625
// ---------------- workspace layout (float units) ----------------
constexpr size_t OF_UNL  = 0;                              // [4][2500][64]  normalized unl, location-major
constexpr size_t OF_SUP  = OF_UNL  + (size_t)4*2500*64;    // [4][5][125][64] normalized support
constexpr size_t OF_SUPT = OF_SUP  + (size_t)4*5*125*64;   // [4][5][64][128] transposed support (pad 125->128)
constexpr size_t OF_QT   = OF_SUPT + (size_t)4*5*64*128;   // [300][64][25]  transposed normalized query
constexpr size_t OF_ROWV = OF_QT   + (size_t)300*64*25;    // [4][5][4nc][2500] f  per-(way,nchunk) row-argmax value
constexpr size_t OF_ROWI = OF_ROWV + (size_t)4*5*4*2500;   // [4][5][4nc][2500] i  per-(way,nchunk) row-argmax n
constexpr size_t OF_CVI  = OF_ROWI + (size_t)4*5*4*2500;   // [4][5][125][20][2] col-argmax partials (v, m)
constexpr size_t OF_CMP  = OF_CVI  + (size_t)4*5*125*20*2; // [4][5][2500] i  compacted unl indices
constexpr size_t OF_CNT  = OF_CMP  + (size_t)4*5*2500;     // [20] i counts
constexpr size_t OF_QV   = OF_CNT  + 20;                   // [300][5] f query_value
constexpr size_t OF_UNEAR= OF_QV   + 1500;                 // [4][2500] i  per-unl-loc nearest support loc
constexpr size_t OF_SNEAR= OF_UNEAR+ 10000;                // [4][625]  i  per-support-loc nearest unl loc

// ============================================================
// Kernel A: L2-normalize all three tensors into ws layouts.
// 16 lanes per location, 4 channels per lane.
// ============================================================
__global__ __launch_bounds__(256) void knorm(
    const float* __restrict__ sup, const float* __restrict__ qry,
    const float* __restrict__ unl,
    float* __restrict__ unl_n, float* __restrict__ sup_n,
    float* __restrict__ supT, float* __restrict__ qt)
{
    int gid = blockIdx.x * 256 + threadIdx.x;
    int loc = gid >> 4;
    int sub = gid & 15;
    if (loc >= 20000) return;

    const float* src;
    float* dst1; int dstr1;
    float* dst2 = nullptr;

    if (loc < 10000) {
        int b = loc / 2500, m = loc % 2500;
        int u = m / 25, hw = m % 25;
        src  = unl + ((size_t)(b*100 + u) * 64) * 25 + hw;   // + c*25
        dst1 = unl_n + (size_t)loc * 64; dstr1 = 1;
    } else if (loc < 12500) {
        int idx = loc - 10000;
        int b = idx / 625, r = idx % 625;
        int w = r / 125,  n = r % 125;
        int shot = n / 25, hw = n % 25;
        src  = sup + ((size_t)(b*25 + w*5 + shot) * 64) * 25 + hw;
        dst1 = sup_n + (size_t)idx * 64; dstr1 = 1;
        dst2 = supT + ((size_t)(b*5 + w) * 64) * 128 + n;    // + c*128
    } else {
        int idx = loc - 12500;
        int bq = idx / 25, mq = idx % 25;
        src  = qry + ((size_t)bq * 64) * 25 + mq;
        dst1 = qt + ((size_t)bq * 64) * 25 + mq; dstr1 = 25;
    }

    float v[4]; float ss = 0.f;
    int c0 = sub * 4;
#pragma unroll
    for (int j = 0; j < 4; ++j) { v[j] = src[(size_t)(c0 + j) * 25]; ss += v[j] * v[j]; }
#pragma unroll
    for (int msk = 1; msk < 16; msk <<= 1) ss += __shfl_xor(ss, msk);
    float sc = 1.f / fmaxf(sqrtf(ss), 1e-12f);
#pragma unroll
    for (int j = 0; j < 4; ++j) {
        float o = v[j] * sc;
        dst1[(size_t)(c0 + j) * dstr1] = o;
        if (dst2) dst2[(size_t)(c0 + j) * 128] = o;
    }
}

// ============================================================
// Kernel B: u2s pass. grid = (b*5+w)*80 + mb*4 + nc = 1600 blocks x 128.
// Each block: 128 m's x 32 n's x 64 c.
// lane-per-m (LDS stride 65 = conflict-free), supT via wave-uniform
// global reads (scalar pipe). 4x the blocks of round-2 for occupancy.
// Outputs: rowv/rowi[b][w][nc][m] (per-(w,nc) row argmax, first-tie)
//          colvi[b][w][n][mb]     (per-mblock col argmax (v,m), min-m tie)
// ============================================================
__global__ __launch_bounds__(128) void kb(
    const float* __restrict__ unl_n, const float* __restrict__ supT,
    float* __restrict__ rowv, int* __restrict__ rowi, float* __restrict__ colvi)
{
    int bid = blockIdx.x;
    int nc = bid & 3;
    int mb = (bid >> 2) % 20;
    int bw = bid / 80;               // b*5+w
    int b  = bw / 5;
    int tid = threadIdx.x;
    int lane = tid & 63, wv = tid >> 6;

    __shared__ float uls[128 * 65];
    __shared__ float sv_[2][32];
    __shared__ int   si_[2][32];

    int m0 = mb * 128;
    // stage 128 unl rows (zero-fill past 2500)
    for (int i = tid; i < 128 * 16; i += 128) {
        int row = i >> 4, c4 = (i & 15) * 4;
        int m = m0 + row;
        float4 x = make_float4(0.f, 0.f, 0.f, 0.f);
        if (m < 2500) x = *(const float4*)(unl_n + ((size_t)(b * 2500 + m)) * 64 + c4);
        uls[row * 65 + c4 + 0] = x.x;
        uls[row * 65 + c4 + 1] = x.y;
        uls[row * 65 + c4 + 2] = x.z;
        uls[row * 65 + c4 + 3] = x.w;
    }
    __syncthreads();

    int m = m0 + tid;
    int n0 = nc * 32;
    int nn = (125 - n0) < 32 ? (125 - n0) : 32;   // 32,32,32,29
    const float* sT = supT + ((size_t)bw * 64) * 128 + n0;
    const float* myrow = &uls[tid * 65];

    float acc[32];
#pragma unroll
    for (int j = 0; j < 32; ++j) acc[j] = 0.f;
    for (int c = 0; c < 64; ++c) {
        float uv = myrow[c];
        const float* srow = sT + c * 128;   // wave-uniform -> scalar loads
#pragma unroll
        for (int j = 0; j < 32; ++j) acc[j] = fmaf(uv, srow[j], acc[j]);
    }

    // row-side running argmax (ascending n within chunk, strict > = first-tie)
    float rbv = NEGINF; int rbi = 0;
    for (int j = 0; j < nn; ++j)
        if (acc[j] > rbv) { rbv = acc[j]; rbi = n0 + j; }
    if (m < 2500) {
        rowv[((size_t)bw * 4 + nc) * 2500 + m] = rbv;
        rowi[((size_t)bw * 4 + nc) * 2500 + m] = rbi;
    }

    // col-side cross-lane argmax (min-m tie)
#pragma unroll
    for (int j = 0; j < 32; ++j) {
        float v = (m < 2500 && j < nn) ? acc[j] : NEGINF;
        int vi = m;
#pragma unroll
        for (int s2 = 1; s2 < 64; s2 <<= 1) {
            float v2 = __shfl_xor(v, s2); int i2 = __shfl_xor(vi, s2);
            if (v2 > v || (v2 == v && i2 < vi)) { v = v2; vi = i2; }
        }
        if (lane == 0) { sv_[wv][j] = v; si_[wv][j] = vi; }
    }
    __syncthreads();
    if (tid < nn) {
        float v = sv_[0][tid]; int vi = si_[0][tid];
        float v2 = sv_[1][tid]; int i2 = si_[1][tid];
        if (v2 > v || (v2 == v && i2 < vi)) { v = v2; vi = i2; }
        float* cv = colvi + ((((size_t)bw) * 125 + (n0 + tid)) * 20 + mb) * 2;
        cv[0] = v; ((int*)cv)[1] = vi;
    }
}

// ============================================================
// Kernel M: grid-parallel merge of row partials (items 0..9999 -> unear,
// now over 5w x 4nc = 20 partials in ascending global-n order)
// and col partials (items 10000..12499 -> snear). 49 blocks x 256.
// ============================================================
__global__ __launch_bounds__(256) void kmerge(
    const float* __restrict__ rowv, const int* __restrict__ rowi,
    const float* __restrict__ colvi,
    int* __restrict__ unear, int* __restrict__ snear)
{
    int it = blockIdx.x * 256 + threadIdx.x;
    if (it < 10000) {
        int b = it / 2500, m = it % 2500;
        float bv = NEGINF; int bi = 0;
#pragma unroll
        for (int w = 0; w < 5; ++w) {
#pragma unroll
            for (int nc = 0; nc < 4; ++nc) {
                size_t o = (((size_t)(b * 5 + w)) * 4 + nc) * 2500 + m;
                float v = rowv[o];
                if (v > bv) { bv = v; bi = w * 125 + rowi[o]; }
            }
        }
        unear[it] = bi;
    } else if (it < 12500) {
        int idx = it - 10000;
        const float* p = colvi + (size_t)idx * 40;
        float bv = NEGINF; int bi = 0x7fffffff;
        for (int mb2 = 0; mb2 < 20; ++mb2) {
            float v = p[mb2 * 2]; int vi = ((const int*)p)[mb2 * 2 + 1];
            if (v > bv || (v == bv && vi < bi)) { bv = v; bi = vi; }
        }
        snear[idx] = bi;
    }
}

// ============================================================
// Kernel P: mutual-NN mask + stable stream compaction.
// One wave per (b,way): 20 blocks x 64 threads.
// ============================================================
__global__ __launch_bounds__(64) void kcmp(
    const int* __restrict__ unear, const int* __restrict__ snear,
    int* __restrict__ cmp, int* __restrict__ cntg)
{
    int p = blockIdx.x;
    int b = p / 5, way = p % 5;
    int lane = threadIdx.x;
    int base = 0;
    for (int mc = 0; mc < 2500; mc += 64) {
        int m = mc + lane;
        bool ok = false;
        if (m < 2500) {
            int un = unear[b * 2500 + m];
            ok = (un / 125 == way) && (snear[b * 625 + un] == m);
        }
        unsigned long long msk = __ballot(ok ? 1 : 0);
        int pre = __popcll(msk & ((1ull << lane) - 1ull));
        if (ok) cmp[(size_t)p * 2500 + base + pre] = m;
        base += __popcll(msk);
    }
    if (lane == 0) cntg[p] = base;
}

// ============================================================
// Kernel C: the hot kernel. One block (256 thr) per (b,q).
// ============================================================
__global__ __launch_bounds__(256) void kc(
    const float* __restrict__ qt, const float* __restrict__ sup_n,
    const float* __restrict__ unl_n, const int* __restrict__ cmp,
    const int* __restrict__ cntg,
    float* __restrict__ qv)
{
    int bq = blockIdx.x;
    int b = bq / 75;
    int tid = threadIdx.x;
    int lane = tid & 63, wv = tid >> 6;

    const float* qtb = qt + (size_t)bq * 64 * 25;
    int cnt[5];
    int L = 0;
#pragma unroll
    for (int i = 0; i < 20; ++i) { int v = cntg[i]; L = L > v ? L : v; }
#pragma unroll
    for (int w = 0; w < 5; ++w) cnt[w] = cntg[b * 5 + w];
    int wb[5];
    { int s = 0;
#pragma unroll
      for (int w = 0; w < 5; ++w) { wb[w] = s; s += 125 + cnt[w]; } }

    __shared__ unsigned char amax_[3136];
    __shared__ float wmaxl[5][25];
    __shared__ float redf[4][25];
    __shared__ int   redi[4][25];
    __shared__ float qmask[25];

    float bestv[25]; int bestp[25];
#pragma unroll
    for (int i = 0; i < 25; ++i) { bestv[i] = NEGINF; bestp[i] = 0x7fffffff; }

    for (int w = 0; w < 5; ++w) {
        float wmx[25];
#pragma unroll
        for (int i = 0; i < 25; ++i) wmx[i] = NEGINF;
        int cw = 125 + cnt[w];

        for (int n = tid; n < cw; n += 256) {
            const float* colp;
            if (n < 125) colp = sup_n + (((size_t)(b * 5 + w)) * 125 + n) * 64;
            else {
                int m = cmp[((size_t)(b * 5 + w)) * 2500 + (n - 125)];
                colp = unl_n + ((size_t)(b * 2500 + m)) * 64;
            }
            float acc[25];
#pragma unroll
            for (int i = 0; i < 25; ++i) acc[i] = 0.f;
            for (int c = 0; c < 64; c += 4) {
                float4 cv = *(const float4*)(colp + c);
                const float* qr = qtb + c * 25;   // block-uniform -> scalar loads
#pragma unroll
                for (int mq = 0; mq < 25; ++mq) {
                    acc[mq] = fmaf(cv.x, qr[mq],      acc[mq]);
                    acc[mq] = fmaf(cv.y, qr[25 + mq], acc[mq]);
                    acc[mq] = fmaf(cv.z, qr[50 + mq], acc[mq]);
                    acc[mq] = fmaf(cv.w, qr[75 + mq], acc[mq]);
                }
            }
            float cmax = NEGINF; int cam = 0;
            int pos = wb[w] + n;
            int pack = ((w * 2625 + n) << 12) | pos;
#pragma unroll
            for (int mq = 0; mq < 25; ++mq) {
                float s = (acc[mq] + 1.0f) * 0.5f;
                if (s > cmax) { cmax = s; cam = mq; }
                wmx[mq] = fmaxf(wmx[mq], s);
                if (s > bestv[mq] || (s == bestv[mq] && pack < bestp[mq])) {
                    bestv[mq] = s; bestp[mq] = pack;
                }
            }
            amax_[pos] = (unsigned char)cam;
        }

        // phantom (all-zero) columns: sim == 0.5, first at n = 125+cnt[w]
        if (L > cnt[w]) {
            int pack = ((w * 2625 + 125 + cnt[w]) << 12) | 0xFFF;
#pragma unroll
            for (int mq = 0; mq < 25; ++mq) {
                float s = 0.5f;
                if (s > bestv[mq] || (s == bestv[mq] && pack < bestp[mq])) {
                    bestv[mq] = s; bestp[mq] = pack;
                }
            }
        }

#pragma unroll
        for (int mq = 0; mq < 25; ++mq) {
            float v = wmx[mq];
#pragma unroll
            for (int s2 = 1; s2 < 64; s2 <<= 1) v = fmaxf(v, __shfl_xor(v, s2));
            wmx[mq] = v;
        }
        if (lane == 0) {
#pragma unroll
            for (int mq = 0; mq < 25; ++mq) redf[wv][mq] = wmx[mq];
        }
        __syncthreads();
        if (tid < 25) {
            float v = fmaxf(fmaxf(redf[0][tid], redf[1][tid]),
                            fmaxf(redf[2][tid], redf[3][tid]));
            if (L > cnt[w]) v = fmaxf(v, 0.5f);
            wmaxl[w][tid] = v;
        }
        __syncthreads();
    }

#pragma unroll
    for (int mq = 0; mq < 25; ++mq) {
        float v = bestv[mq]; int p = bestp[mq];
#pragma unroll
        for (int s2 = 1; s2 < 64; s2 <<= 1) {
            float v2 = __shfl_xor(v, s2); int p2 = __shfl_xor(p, s2);
            if (v2 > v || (v2 == v && p2 < p)) { v = v2; p = p2; }
        }
        bestv[mq] = v; bestp[mq] = p;
    }
    if (lane == 0) {
#pragma unroll
        for (int mq = 0; mq < 25; ++mq) { redf[wv][mq] = bestv[mq]; redi[wv][mq] = bestp[mq]; }
    }
    __syncthreads();
    if (tid < 25) {
        float v = redf[0][tid]; int p = redi[0][tid];
#pragma unroll
        for (int k = 1; k < 4; ++k) {
            float v2 = redf[k][tid]; int p2 = redi[k][tid];
            if (v2 > v || (v2 == v && p2 < p)) { v = v2; p = p2; }
        }
        int pos = p & 0xFFF;
        int g = (pos == 0xFFF) ? 0 : (int)amax_[pos];
        qmask[tid] = (g == tid) ? 1.0f : 0.0f;
    }
    __syncthreads();
    if (tid < 5) {
        float s = 0.f;
#pragma unroll
        for (int mq = 0; mq < 25; ++mq) s += wmaxl[tid][mq] * qmask[mq];
        qv[(size_t)bq * 5 + tid] = s;
    }
}

// ============================================================
// Kernel D: cross-entropy loss over 300 rows of 5 logits.
// ============================================================
__global__ __launch_bounds__(256) void kd(
    const float* __restrict__ qv, const int* __restrict__ qy,
    float* __restrict__ out)
{
    __shared__ float part[256];
    int tid = threadIdx.x;
    float s = 0.f;
    for (int r = tid; r < 300; r += 256) {
        const float* l = qv + (size_t)r * 5;
        int y = qy[r];
        float mx = l[0];
#pragma unroll
        for (int w = 1; w < 5; ++w) mx = fmaxf(mx, l[w]);
        float se = 0.f;
#pragma unroll
        for (int w = 0; w < 5; ++w) se += expf(l[w] - mx);
        s += -(l[y] - mx - logf(se));
    }
    part[tid] = s;
    __syncthreads();
    for (int st = 128; st > 0; st >>= 1) {
        if (tid < st) part[tid] += part[tid + st];
        __syncthreads();
    }
    if (tid == 0) out[0] = part[0] / 300.0f;
}

// ============================================================
extern "C" void kernel_launch(void* const* d_in, const int* in_sizes, int n_in,
                              void* d_out, int out_size, void* d_ws, size_t ws_size,
                              hipStream_t stream)
{
    const float* sup = (const float*)d_in[0];
    const float* qry = (const float*)d_in[2];
    const int*   qy  = (const int*)d_in[3];
    const float* unl = (const float*)d_in[4];

    float* ws    = (float*)d_ws;
    float* unl_n = ws + OF_UNL;
    float* sup_n = ws + OF_SUP;
    float* supT  = ws + OF_SUPT;
    float* qt    = ws + OF_QT;
    float* rowv  = ws + OF_ROWV;
    int*   rowi  = (int*)(ws + OF_ROWI);
    float* colvi = ws + OF_CVI;
    int*   cmp   = (int*)(ws + OF_CMP);
    int*   cntg  = (int*)(ws + OF_CNT);
    float* qv    = ws + OF_QV;
    int*   unear = (int*)(ws + OF_UNEAR);
    int*   snear = (int*)(ws + OF_SNEAR);

    hipLaunchKernelGGL(knorm, dim3(1250), dim3(256), 0, stream,
                       sup, qry, unl, unl_n, sup_n, supT, qt);
    hipLaunchKernelGGL(kb, dim3(1600), dim3(128), 0, stream,
                       unl_n, supT, rowv, rowi, colvi);
    hipLaunchKernelGGL(kmerge, dim3(49), dim3(256), 0, stream,
                       rowv, rowi, colvi, unear, snear);
    hipLaunchKernelGGL(kcmp, dim3(20), dim3(64), 0, stream,
                       unear, snear, cmp, cntg);
    hipLaunchKernelGGL(kc, dim3(300), dim3(256), 0, stream,
                       qt, sup_n, unl_n, cmp, cntg, qv);
    hipLaunchKernelGGL(kd, dim3(1), dim3(256), 0, stream,
                       qv, qy, (float*)d_out);
}

// Round 4
// 243.740 us; speedup vs baseline: 1.8183x; 1.0330x over previous
//
#include <hip/hip_runtime.h>

#define NEGINF (-1e30f)

// ---------------- problem constants ----------------
// b=4, c=64, h=w=5, q=75, u=100, N_WAY=5, K_SHOT=5
// M_s = 125 (per way), M_u = 2500, M_q = 25, M_tot = 2625
// ---------------- workspace layout (float units) ----------------
constexpr size_t OF_UNL  = 0;                              // [4][2500][64]  normalized unl, location-major
constexpr size_t OF_SUP  = OF_UNL  + (size_t)4*2500*64;    // [4][5][125][64] normalized support
constexpr size_t OF_SUPT = OF_SUP  + (size_t)4*5*125*64;   // [4][5][64][128] transposed support (pad 125->128)
constexpr size_t OF_QT   = OF_SUPT + (size_t)4*5*64*128;   // [300][64][25]  transposed normalized query
constexpr size_t OF_ROWV = OF_QT   + (size_t)300*64*25;    // [4][5][4nc][2500] f  per-(way,nchunk) row-argmax value
constexpr size_t OF_ROWI = OF_ROWV + (size_t)4*5*4*2500;   // [4][5][4nc][2500] i  per-(way,nchunk) row-argmax n
constexpr size_t OF_CVI  = OF_ROWI + (size_t)4*5*4*2500;   // [4][5][125][20][2] col-argmax partials (v, m)
constexpr size_t OF_CMP  = OF_CVI  + (size_t)4*5*125*20*2; // [4][5][2500] i  compacted unl indices
constexpr size_t OF_CNT  = OF_CMP  + (size_t)4*5*2500;     // [20] i counts
constexpr size_t OF_QV   = OF_CNT  + 20;                   // [300][5] f query_value
constexpr size_t OF_UNEAR= OF_QV   + 1500;                 // [4][2500] i
constexpr size_t OF_SNEAR= OF_UNEAR+ 10000;                // [4][625]  i
constexpr size_t OF_WMX  = OF_SNEAR+ 2500;                 // [300][5][25] f  per-way max over cols
constexpr size_t OF_BV   = OF_WMX  + 37500;                // [300][5][25] f  per-way best val
constexpr size_t OF_BP   = OF_BV   + 37500;                // [300][5][25] i  per-way best pack
constexpr size_t OF_AMX  = OF_BP   + 37500;                // [300][3200] u8  per-col argmax-over-mq

// ============================================================
// Kernel A: L2-normalize all three tensors into ws layouts.
// ============================================================
__global__ __launch_bounds__(256) void knorm(
    const float* __restrict__ sup, const float* __restrict__ qry,
    const float* __restrict__ unl,
    float* __restrict__ unl_n, float* __restrict__ sup_n,
    float* __restrict__ supT, float* __restrict__ qt)
{
    int gid = blockIdx.x * 256 + threadIdx.x;
    int loc = gid >> 4;
    int sub = gid & 15;
    if (loc >= 20000) return;

    const float* src;
    float* dst1; int dstr1;
    float* dst2 = nullptr;

    if (loc < 10000) {
        int b = loc / 2500, m = loc % 2500;
        int u = m / 25, hw = m % 25;
        src  = unl + ((size_t)(b*100 + u) * 64) * 25 + hw;
        dst1 = unl_n + (size_t)loc * 64; dstr1 = 1;
    } else if (loc < 12500) {
        int idx = loc - 10000;
        int b = idx / 625, r = idx % 625;
        int w = r / 125,  n = r % 125;
        int shot = n / 25, hw = n % 25;
        src  = sup + ((size_t)(b*25 + w*5 + shot) * 64) * 25 + hw;
        dst1 = sup_n + (size_t)idx * 64; dstr1 = 1;
        dst2 = supT + ((size_t)(b*5 + w) * 64) * 128 + n;
    } else {
        int idx = loc - 12500;
        int bq = idx / 25, mq = idx % 25;
        src  = qry + ((size_t)bq * 64) * 25 + mq;
        dst1 = qt + ((size_t)bq * 64) * 25 + mq; dstr1 = 25;
    }

    float v[4]; float ss = 0.f;
    int c0 = sub * 4;
#pragma unroll
    for (int j = 0; j < 4; ++j) { v[j] = src[(size_t)(c0 + j) * 25]; ss += v[j] * v[j]; }
#pragma unroll
    for (int msk = 1; msk < 16; msk <<= 1) ss += __shfl_xor(ss, msk);
    float sc = 1.f / fmaxf(sqrtf(ss), 1e-12f);
#pragma unroll
    for (int j = 0; j < 4; ++j) {
        float o = v[j] * sc;
        dst1[(size_t)(c0 + j) * dstr1] = o;
        if (dst2) dst2[(size_t)(c0 + j) * 128] = o;
    }
}

// ============================================================
// Kernel B: u2s pass. 1600 blocks x 128 (128 m x 32 n x 64 c each).
// ============================================================
__global__ __launch_bounds__(128) void kb(
    const float* __restrict__ unl_n, const float* __restrict__ supT,
    float* __restrict__ rowv, int* __restrict__ rowi, float* __restrict__ colvi)
{
    int bid = blockIdx.x;
    int nc = bid & 3;
    int mb = (bid >> 2) % 20;
    int bw = bid / 80;               // b*5+w
    int b  = bw / 5;
    int tid = threadIdx.x;
    int lane = tid & 63, wv = tid >> 6;

    __shared__ float uls[128 * 65];
    __shared__ float sv_[2][32];
    __shared__ int   si_[2][32];

    int m0 = mb * 128;
    for (int i = tid; i < 128 * 16; i += 128) {
        int row = i >> 4, c4 = (i & 15) * 4;
        int m = m0 + row;
        float4 x = make_float4(0.f, 0.f, 0.f, 0.f);
        if (m < 2500) x = *(const float4*)(unl_n + ((size_t)(b * 2500 + m)) * 64 + c4);
        uls[row * 65 + c4 + 0] = x.x;
        uls[row * 65 + c4 + 1] = x.y;
        uls[row * 65 + c4 + 2] = x.z;
        uls[row * 65 + c4 + 3] = x.w;
    }
    __syncthreads();

    int m = m0 + tid;
    int n0 = nc * 32;
    int nn = (125 - n0) < 32 ? (125 - n0) : 32;
    const float* sT = supT + ((size_t)bw * 64) * 128 + n0;
    const float* myrow = &uls[tid * 65];

    float acc[32];
#pragma unroll
    for (int j = 0; j < 32; ++j) acc[j] = 0.f;
    for (int c = 0; c < 64; ++c) {
        float uv = myrow[c];
        const float* srow = sT + c * 128;
#pragma unroll
        for (int j = 0; j < 32; ++j) acc[j] = fmaf(uv, srow[j], acc[j]);
    }

    float rbv = NEGINF; int rbi = 0;
    for (int j = 0; j < nn; ++j)
        if (acc[j] > rbv) { rbv = acc[j]; rbi = n0 + j; }
    if (m < 2500) {
        rowv[((size_t)bw * 4 + nc) * 2500 + m] = rbv;
        rowi[((size_t)bw * 4 + nc) * 2500 + m] = rbi;
    }

#pragma unroll
    for (int j = 0; j < 32; ++j) {
        float v = (m < 2500 && j < nn) ? acc[j] : NEGINF;
        int vi = m;
#pragma unroll
        for (int s2 = 1; s2 < 64; s2 <<= 1) {
            float v2 = __shfl_xor(v, s2); int i2 = __shfl_xor(vi, s2);
            if (v2 > v || (v2 == v && i2 < vi)) { v = v2; vi = i2; }
        }
        if (lane == 0) { sv_[wv][j] = v; si_[wv][j] = vi; }
    }
    __syncthreads();
    if (tid < nn) {
        float v = sv_[0][tid]; int vi = si_[0][tid];
        float v2 = sv_[1][tid]; int i2 = si_[1][tid];
        if (v2 > v || (v2 == v && i2 < vi)) { v = v2; vi = i2; }
        float* cv = colvi + ((((size_t)bw) * 125 + (n0 + tid)) * 20 + mb) * 2;
        cv[0] = v; ((int*)cv)[1] = vi;
    }
}

// ============================================================
// Kernel M: merge row partials -> unear, col partials -> snear.
// ============================================================
__global__ __launch_bounds__(256) void kmerge(
    const float* __restrict__ rowv, const int* __restrict__ rowi,
    const float* __restrict__ colvi,
    int* __restrict__ unear, int* __restrict__ snear)
{
    int it = blockIdx.x * 256 + threadIdx.x;
    if (it < 10000) {
        int b = it / 2500, m = it % 2500;
        float bv = NEGINF; int bi = 0;
#pragma unroll
        for (int w = 0; w < 5; ++w) {
#pragma unroll
            for (int nc = 0; nc < 4; ++nc) {
                size_t o = (((size_t)(b * 5 + w)) * 4 + nc) * 2500 + m;
                float v = rowv[o];
                if (v > bv) { bv = v; bi = w * 125 + rowi[o]; }
            }
        }
        unear[it] = bi;
    } else if (it < 12500) {
        int idx = it - 10000;
        const float* p = colvi + (size_t)idx * 40;
        float bv = NEGINF; int bi = 0x7fffffff;
        for (int mb2 = 0; mb2 < 20; ++mb2) {
            float v = p[mb2 * 2]; int vi = ((const int*)p)[mb2 * 2 + 1];
            if (v > bv || (v == bv && vi < bi)) { bv = v; bi = vi; }
        }
        snear[idx] = bi;
    }
}

// ============================================================
// Kernel P: mutual-NN mask + stable stream compaction. 20 blocks x 64.
// ============================================================
__global__ __launch_bounds__(64) void kcmp(
    const int* __restrict__ unear, const int* __restrict__ snear,
    int* __restrict__ cmp, int* __restrict__ cntg)
{
    int p = blockIdx.x;
    int b = p / 5, way = p % 5;
    int lane = threadIdx.x;
    int base = 0;
    for (int mc = 0; mc < 2500; mc += 64) {
        int m = mc + lane;
        bool ok = false;
        if (m < 2500) {
            int un = unear[b * 2500 + m];
            ok = (un / 125 == way) && (snear[b * 625 + un] == m);
        }
        unsigned long long msk = __ballot(ok ? 1 : 0);
        int pre = __popcll(msk & ((1ull << lane) - 1ull));
        if (ok) cmp[(size_t)p * 2500 + base + pre] = m;
        base += __popcll(msk);
    }
    if (lane == 0) cntg[p] = base;
}

// ============================================================
// Kernel C1: query similarity, one block (256 thr) per (bq, way).
// Grid 1500 = 5x round-3's parallelism; one reduction phase.
// Writes per-way partials: wmxg/bvg/bpg[bq][w][25], amaxg[bq][pos].
// pack = ((w*2625+n)<<12)|pos encodes the reference's global flat
// column order (w*M_tot+n) for exact first-index tie-breaks.
// ============================================================
__global__ __launch_bounds__(256) void kc1(
    const float* __restrict__ qt, const float* __restrict__ sup_n,
    const float* __restrict__ unl_n, const int* __restrict__ cmp,
    const int* __restrict__ cntg,
    float* __restrict__ wmxg, float* __restrict__ bvg,
    int* __restrict__ bpg, unsigned char* __restrict__ amaxg)
{
    int bid = blockIdx.x;
    int w = bid % 5, bq = bid / 5;
    int b = bq / 75;
    int tid = threadIdx.x;
    int lane = tid & 63, wv = tid >> 6;

    const float* qtb = qt + (size_t)bq * 64 * 25;

    int L = 0;
#pragma unroll
    for (int i = 0; i < 20; ++i) { int v = cntg[i]; L = L > v ? L : v; }
    int cntw = 0, wb = 0;
#pragma unroll
    for (int w2 = 0; w2 < 5; ++w2) {
        int c2 = cntg[b * 5 + w2];
        if (w2 < w) wb += 125 + c2;
        if (w2 == w) cntw = c2;
    }
    int cw = 125 + cntw;

    __shared__ float redw[4][25];
    __shared__ float redf[4][25];
    __shared__ int   redi[4][25];

    float wmx[25], bestv[25]; int bestp[25];
#pragma unroll
    for (int i = 0; i < 25; ++i) { wmx[i] = NEGINF; bestv[i] = NEGINF; bestp[i] = 0x7fffffff; }

    for (int n = tid; n < cw; n += 256) {
        const float* colp;
        if (n < 125) colp = sup_n + (((size_t)(b * 5 + w)) * 125 + n) * 64;
        else {
            int m = cmp[((size_t)(b * 5 + w)) * 2500 + (n - 125)];
            colp = unl_n + ((size_t)(b * 2500 + m)) * 64;
        }
        float acc[25];
#pragma unroll
        for (int i = 0; i < 25; ++i) acc[i] = 0.f;
        for (int c = 0; c < 64; c += 4) {
            float4 cv = *(const float4*)(colp + c);
            const float* qr = qtb + c * 25;   // block-uniform -> scalar loads
#pragma unroll
            for (int mq = 0; mq < 25; ++mq) {
                acc[mq] = fmaf(cv.x, qr[mq],      acc[mq]);
                acc[mq] = fmaf(cv.y, qr[25 + mq], acc[mq]);
                acc[mq] = fmaf(cv.z, qr[50 + mq], acc[mq]);
                acc[mq] = fmaf(cv.w, qr[75 + mq], acc[mq]);
            }
        }
        float cmax = NEGINF; int cam = 0;
        int pos = wb + n;
        int pack = ((w * 2625 + n) << 12) | pos;
#pragma unroll
        for (int mq = 0; mq < 25; ++mq) {
            float s = (acc[mq] + 1.0f) * 0.5f;
            if (s > cmax) { cmax = s; cam = mq; }
            wmx[mq] = fmaxf(wmx[mq], s);
            if (s > bestv[mq] || (s == bestv[mq] && pack < bestp[mq])) {
                bestv[mq] = s; bestp[mq] = pack;
            }
        }
        amaxg[(size_t)bq * 3200 + pos] = (unsigned char)cam;
    }

    // phantom (all-zero) columns: sim == 0.5, first at n = 125+cntw
    if (L > cntw) {
        int pack = ((w * 2625 + 125 + cntw) << 12) | 0xFFF;
#pragma unroll
        for (int mq = 0; mq < 25; ++mq) {
            if (0.5f > bestv[mq] || (0.5f == bestv[mq] && pack < bestp[mq])) {
                bestv[mq] = 0.5f; bestp[mq] = pack;
            }
        }
    }

    // single cross-wave reduction phase (wmax + best together)
#pragma unroll
    for (int mq = 0; mq < 25; ++mq) {
        float m2 = wmx[mq];
        float v = bestv[mq]; int p = bestp[mq];
#pragma unroll
        for (int s2 = 1; s2 < 64; s2 <<= 1) {
            m2 = fmaxf(m2, __shfl_xor(m2, s2));
            float v2 = __shfl_xor(v, s2); int p2 = __shfl_xor(p, s2);
            if (v2 > v || (v2 == v && p2 < p)) { v = v2; p = p2; }
        }
        wmx[mq] = m2; bestv[mq] = v; bestp[mq] = p;
    }
    if (lane == 0) {
#pragma unroll
        for (int mq = 0; mq < 25; ++mq) {
            redw[wv][mq] = wmx[mq]; redf[wv][mq] = bestv[mq]; redi[wv][mq] = bestp[mq];
        }
    }
    __syncthreads();
    if (tid < 25) {
        float m2 = fmaxf(fmaxf(redw[0][tid], redw[1][tid]),
                         fmaxf(redw[2][tid], redw[3][tid]));
        if (L > cntw) m2 = fmaxf(m2, 0.5f);
        float v = redf[0][tid]; int p = redi[0][tid];
#pragma unroll
        for (int k = 1; k < 4; ++k) {
            float v2 = redf[k][tid]; int p2 = redi[k][tid];
            if (v2 > v || (v2 == v && p2 < p)) { v = v2; p = p2; }
        }
        size_t o = ((size_t)bq * 5 + w) * 25 + tid;
        wmxg[o] = m2; bvg[o] = v; bpg[o] = p;
    }
}

// ============================================================
// Kernel CE: merge 5 way-partials per (bq,mq), build mutual mask,
// emit query_value. 300 blocks x 64.
// ============================================================
__global__ __launch_bounds__(64) void kce(
    const float* __restrict__ wmxg, const float* __restrict__ bvg,
    const int* __restrict__ bpg, const unsigned char* __restrict__ amaxg,
    float* __restrict__ qv)
{
    int bq = blockIdx.x;
    int tid = threadIdx.x;
    __shared__ float qmask[25];
    if (tid < 25) {
        float v = NEGINF; int p = 0x7fffffff;
#pragma unroll
        for (int w = 0; w < 5; ++w) {
            size_t o = ((size_t)bq * 5 + w) * 25 + tid;
            float v2 = bvg[o]; int p2 = bpg[o];
            if (v2 > v || (v2 == v && p2 < p)) { v = v2; p = p2; }
        }
        int pos = p & 0xFFF;
        int g = (pos == 0xFFF) ? 0 : (int)amaxg[(size_t)bq * 3200 + pos];
        qmask[tid] = (g == tid) ? 1.0f : 0.0f;
    }
    __syncthreads();
    if (tid < 5) {
        float s = 0.f;
#pragma unroll
        for (int mq = 0; mq < 25; ++mq)
            s += wmxg[((size_t)bq * 5 + tid) * 25 + mq] * qmask[mq];
        qv[(size_t)bq * 5 + tid] = s;
    }
}

// ============================================================
// Kernel D: cross-entropy loss over 300 rows of 5 logits.
// ============================================================
__global__ __launch_bounds__(256) void kd(
    const float* __restrict__ qv, const int* __restrict__ qy,
    float* __restrict__ out)
{
    __shared__ float part[256];
    int tid = threadIdx.x;
    float s = 0.f;
    for (int r = tid; r < 300; r += 256) {
        const float* l = qv + (size_t)r * 5;
        int y = qy[r];
        float mx = l[0];
#pragma unroll
        for (int w = 1; w < 5; ++w) mx = fmaxf(mx, l[w]);
        float se = 0.f;
#pragma unroll
        for (int w = 0; w < 5; ++w) se += expf(l[w] - mx);
        s += -(l[y] - mx - logf(se));
    }
    part[tid] = s;
    __syncthreads();
    for (int st = 128; st > 0; st >>= 1) {
        if (tid < st) part[tid] += part[tid + st];
        __syncthreads();
    }
    if (tid == 0) out[0] = part[0] / 300.0f;
}

// ============================================================
extern "C" void kernel_launch(void* const* d_in, const int* in_sizes, int n_in,
                              void* d_out, int out_size, void* d_ws, size_t ws_size,
                              hipStream_t stream)
{
    const float* sup = (const float*)d_in[0];
    const float* qry = (const float*)d_in[2];
    const int*   qy  = (const int*)d_in[3];
    const float* unl = (const float*)d_in[4];

    float* ws    = (float*)d_ws;
    float* unl_n = ws + OF_UNL;
    float* sup_n = ws + OF_SUP;
    float* supT  = ws + OF_SUPT;
    float* qt    = ws + OF_QT;
    float* rowv  = ws + OF_ROWV;
    int*   rowi  = (int*)(ws + OF_ROWI);
    float* colvi = ws + OF_CVI;
    int*   cmp   = (int*)(ws + OF_CMP);
    int*   cntg  = (int*)(ws + OF_CNT);
    float* qv    = ws + OF_QV;
    int*   unear = (int*)(ws + OF_UNEAR);
    int*   snear = (int*)(ws + OF_SNEAR);
    float* wmxg  = ws + OF_WMX;
    float* bvg   = ws + OF_BV;
    int*   bpg   = (int*)(ws + OF_BP);
    unsigned char* amaxg = (unsigned char*)(ws + OF_AMX);

    hipLaunchKernelGGL(knorm, dim3(1250), dim3(256), 0, stream,
                       sup, qry, unl, unl_n, sup_n, supT, qt);
    hipLaunchKernelGGL(kb, dim3(1600), dim3(128), 0, stream,
                       unl_n, supT, rowv, rowi, colvi);
    hipLaunchKernelGGL(kmerge, dim3(49), dim3(256), 0, stream,
                       rowv, rowi, colvi, unear, snear);
    hipLaunchKernelGGL(kcmp, dim3(20), dim3(64), 0, stream,
                       unear, snear, cmp, cntg);
    hipLaunchKernelGGL(kc1, dim3(1500), dim3(256), 0, stream,
                       qt, sup_n, unl_n, cmp, cntg, wmxg, bvg, bpg, amaxg);
    hipLaunchKernelGGL(kce, dim3(300), dim3(64), 0, stream,
                       wmxg, bvg, bpg, amaxg, qv);
    hipLaunchKernelGGL(kd, dim3(1), dim3(256), 0, stream,
                       qv, qy, (float*)d_out);
}